// Round 11
// baseline (727.358 us; speedup 1.0000x reference)
//
#include <hip/hip_runtime.h>
#include <math.h>

#define S_TOK 16384
#define DDIM  4096
#define NEXP  64
#define CAP   256
#define NB    256               // 64-token bookkeeping blocks
#define SPLITS 8
#define KRANGE (DDIM / SPLITS)  // 512
#define KT    32
#define NTILE (KRANGE / KT)     // 16
#define MTILES (S_TOK / 64)     // 256

// global -> LDS direct DMA, 16B per lane (dest = wave-uniform base + lane*16)
__device__ __forceinline__ void gload_lds16(const float* g, float* l)
{
    __builtin_amdgcn_global_load_lds(
        (const __attribute__((address_space(1))) void*)g,
        (__attribute__((address_space(3))) void*)l, 16, 0, 0);
}

// ---------------------------------------------------------------------------
// Router GEMM, token-per-lane. Block = 1 wave = 64 tokens; acc[64] = full
// expert row per thread. B (wg) read at wave-uniform addresses -> scalar
// loads (SGPR operand in v_fma). A staged via global_load_lds with XOR
// line-swizzle: logical line L = tok*8+kc stored at P = L ^ (tok&7)
// (involution; makes per-kc reads bank-spread while LDS stays linear).
// Single-wave block: explicit vmcnt(0) drain guards against s_barrier
// elision dropping the LDS-DMA wait (defensive; multi-wave barrier would
// have performed exactly this wait).
// ATOMIC=0: write partial[s][S][E]. ATOMIC=1: atomicAdd into logits[S][E].
// ---------------------------------------------------------------------------
template <int ATOMIC>
__global__ __launch_bounds__(64, 4) void gemm_tok_kernel(
    const float* __restrict__ x, const float* __restrict__ wg,
    float* __restrict__ outbuf)
{
    __shared__ float AT[2][KT * 64];  // 2 x 8 KB double buffer

    const int t   = threadIdx.x;      // lane = token within tile
    const int blk = blockIdx.x;
    const int m   = blk & (MTILES - 1);
    const int s   = blk >> 8;         // split id (MTILES = 256)
    const int mBase = m * 64;
    const int kBase = s * KRANGE;

    float acc[NEXP] = {};             // 64 VGPR accumulator

    auto stage = [&](int buf, int tile) {
        const int k0 = kBase + tile * KT;
#pragma unroll
        for (int c = 0; c < 8; c++) {
            int P   = c * 64 + t;             // LDS 16B-line index (linear)
            int tok = P >> 3;
            int kc  = (P & 7) ^ (tok & 7);    // inverse swizzle on source
            gload_lds16(&x[(size_t)(mBase + tok) * DDIM + k0 + kc * 4],
                        &AT[buf][P * 4]);
        }
    };

    stage(0, 0);
    for (int tile = 0; tile < NTILE; tile++) {
        asm volatile("s_waitcnt vmcnt(0)" ::: "memory");  // LDS-DMA landed
        __syncthreads();
        if (tile + 1 < NTILE) stage((tile + 1) & 1, tile + 1);  // in flight
        const int k0 = kBase + tile * KT;
        const float* At = AT[tile & 1];
#pragma unroll
        for (int kc = 0; kc < 8; kc++) {
            float4 a4 = *reinterpret_cast<const float4*>(
                &At[(t * 8 + (kc ^ (t & 7))) * 4]);
#pragma unroll
            for (int j = 0; j < 4; j++) {
                const float a = (&a4.x)[j];
                const float4* bk = reinterpret_cast<const float4*>(
                    &wg[(size_t)(k0 + kc * 4 + j) * NEXP]);   // wave-uniform
#pragma unroll
                for (int e4 = 0; e4 < 16; e4++) {
                    float4 b = bk[e4];
                    acc[e4 * 4 + 0] = fmaf(a, b.x, acc[e4 * 4 + 0]);
                    acc[e4 * 4 + 1] = fmaf(a, b.y, acc[e4 * 4 + 1]);
                    acc[e4 * 4 + 2] = fmaf(a, b.z, acc[e4 * 4 + 2]);
                    acc[e4 * 4 + 3] = fmaf(a, b.w, acc[e4 * 4 + 3]);
                }
            }
        }
    }

    const size_t row = (size_t)(mBase + t) * NEXP;
    if (ATOMIC) {
#pragma unroll
        for (int e = 0; e < NEXP; e++) atomicAdd(&outbuf[row + e], acc[e]);
    } else {
        float* dst = outbuf + (size_t)s * ((size_t)S_TOK * NEXP) + row;
#pragma unroll
        for (int e4 = 0; e4 < 16; e4++)
            reinterpret_cast<float4*>(dst)[e4] =
                make_float4(acc[e4 * 4 + 0], acc[e4 * 4 + 1],
                            acc[e4 * 4 + 2], acc[e4 * 4 + 3]);
    }
}

// ---------------------------------------------------------------------------
// Per-token softmax/argmax/stats. One token per lane; 256 tokens per block.
// buf: nsplits==1 -> logits[S][E]; else partial[nsplits][S][E] (summed here).
// ---------------------------------------------------------------------------
__global__ __launch_bounds__(256) void softmax_kernel(
    const float* __restrict__ buf, int nsplits,
    int* __restrict__ arg_idx, float* __restrict__ gateval,
    int* __restrict__ cnt_part, float* __restrict__ gsum_blk)
{
    __shared__ int   cnt_sh[4][NEXP];
    __shared__ float gs_sh[NEXP];
    const int t = threadIdx.x;
    const int w = t >> 6, lane = t & 63;
    const int tok = blockIdx.x * 256 + t;

    if (t < NEXP) gs_sh[t] = 0.f;
    cnt_sh[w][lane] = 0;
    __syncthreads();

    float4 r[16];
    {
        const float* p = buf + (size_t)tok * NEXP;
#pragma unroll
        for (int q = 0; q < 16; q++)
            r[q] = *reinterpret_cast<const float4*>(p + q * 4);
    }
    for (int sp = 1; sp < nsplits; sp++) {
        const float* ps = buf + (size_t)sp * ((size_t)S_TOK * NEXP)
                              + (size_t)tok * NEXP;
#pragma unroll
        for (int q = 0; q < 16; q++) {
            float4 v = *reinterpret_cast<const float4*>(ps + q * 4);
            r[q].x += v.x; r[q].y += v.y; r[q].z += v.z; r[q].w += v.w;
        }
    }

    float m_ = r[0].x; int b_ = 0;
#pragma unroll
    for (int q = 0; q < 16; q++)
#pragma unroll
        for (int j = 0; j < 4; j++) {
            float v = (&r[q].x)[j];
            int e = q * 4 + j;
            if (v > m_) { m_ = v; b_ = e; }   // strict > keeps first occurrence
        }

    float den = 0.f;
#pragma unroll
    for (int q = 0; q < 16; q++)
#pragma unroll
        for (int j = 0; j < 4; j++) {
            float g = __expf((&r[q].x)[j] - m_);
            (&r[q].x)[j] = g;
            den += g;
        }
    float inv = 1.f / den;

    arg_idx[tok] = b_;
    gateval[tok] = inv;                       // gate of argmax = exp(0)/den
    atomicAdd(&cnt_sh[w][b_], 1);

    // per-expert gate sums: wave butterfly per expert (static-indexed)
#pragma unroll
    for (int q = 0; q < 16; q++)
#pragma unroll
        for (int j = 0; j < 4; j++) {
            float v = (&r[q].x)[j] * inv;
#pragma unroll
            for (int msk = 1; msk < 64; msk <<= 1) v += __shfl_xor(v, msk, 64);
            if (lane == 0) atomicAdd(&gs_sh[q * 4 + j], v);
        }

    __syncthreads();
    cnt_part[(blockIdx.x * 4 + w) * NEXP + lane] = cnt_sh[w][lane];
    if (t < NEXP) gsum_blk[blockIdx.x * NEXP + t] = gs_sh[t];
}

// ---------------------------------------------------------------------------
// Per-expert exclusive prefix over 256 block counts + loss.
// ---------------------------------------------------------------------------
__global__ __launch_bounds__(256) void scan_kernel(
    const int* __restrict__ cnt_part, const float* __restrict__ gsum_blk,
    int* __restrict__ offsets, float* __restrict__ loss_out)
{
    __shared__ int qs[4][NEXP];
    const int t = threadIdx.x;
    const int e = t & 63, q = t >> 6;

    int s = 0;
    for (int i = 0; i < 64; i++) s += cnt_part[(q * 64 + i) * NEXP + e];
    qs[q][e] = s;
    __syncthreads();

    int base = 0;
    for (int q2 = 0; q2 < q; q2++) base += qs[q2][e];
    int run = base;
    for (int i = 0; i < 64; i++) {
        int b = q * 64 + i;
        offsets[b * NEXP + e] = run;
        run += cnt_part[b * NEXP + e];
    }

    if (q == 0) {   // threads 0..63 = one wave
        float totg = 0.f;
        for (int i = 0; i < 64; i++) totg += gsum_blk[i * NEXP + e];
        int totc = qs[0][e] + qs[1][e] + qs[2][e] + qs[3][e];
        float lp = (totg / (float)S_TOK) * ((float)totc / (float)S_TOK);
#pragma unroll
        for (int msk = 1; msk < 64; msk <<= 1) lp += __shfl_xor(lp, msk, 64);
        if (t == 0) loss_out[0] = 0.01f * (float)NEXP * lp;
    }
}

// ---------------------------------------------------------------------------
// Per-token rank within its 64-token block -> dispatch slots.
// ---------------------------------------------------------------------------
__global__ __launch_bounds__(64) void dispatch_kernel(
    const int* __restrict__ arg_idx, const float* __restrict__ gateval,
    const int* __restrict__ offsets,
    float* __restrict__ out_gates, float* __restrict__ out_disp)
{
    __shared__ int sh_e[64];
    const int t = threadIdx.x, blk = blockIdx.x;
    const int tok = blk * 64 + t;
    const int e = arg_idx[tok];
    sh_e[t] = e;
    __syncthreads();
    int rank = 0;
    for (int j = 0; j < t; j++) rank += (sh_e[j] == e);
    int loc = offsets[blk * NEXP + e] + rank;
    float gv = 0.f;
    if (loc < CAP) {
        gv = gateval[tok];
        out_disp[e * CAP + loc] = (float)tok;
    }
    out_gates[tok] = gv;
}

__global__ __launch_bounds__(256) void init_disp_kernel(float* __restrict__ p)
{
    p[blockIdx.x * 256 + threadIdx.x] = -1.0f;
}

__global__ __launch_bounds__(256) void zero_kernel(float* __restrict__ p, int n4)
{
    int i = blockIdx.x * 256 + threadIdx.x;
    float4 z = make_float4(0.f, 0.f, 0.f, 0.f);
    for (; i < n4; i += gridDim.x * 256)
        reinterpret_cast<float4*>(p)[i] = z;
}

// ---------------------------------------------------------------------------
extern "C" void kernel_launch(void* const* d_in, const int* in_sizes, int n_in,
                              void* d_out, int out_size, void* d_ws, size_t ws_size,
                              hipStream_t stream)
{
    const float* x  = (const float*)d_in[0];
    const float* wg = (const float*)d_in[1];

    float* out       = (float*)d_out;
    float* out_loss  = out;                 // [0]
    float* out_gates = out + 1;             // [1 .. S]
    float* out_disp  = out + 1 + S_TOK;     // [1+S ..)

    char* ws = (char*)d_ws;
    int*   arg_idx  = (int*)(ws);                   // 64 KB
    float* gateval  = (float*)(ws + (64 << 10));    // 64 KB
    int*   cnt_part = (int*)(ws + (128 << 10));     // 64 KB
    float* gsum_blk = (float*)(ws + (192 << 10));   // 16 KB
    int*   offsets  = (int*)(ws + (208 << 10));     // 64 KB
    float* buf      = (float*)(ws + (512 << 10));   // logits or partials

    const size_t splitBytes = (size_t)SPLITS * S_TOK * NEXP * sizeof(float);
    const bool use_split = ws_size >= (512u << 10) + splitBytes;

    hipLaunchKernelGGL(init_disp_kernel, dim3(NEXP * CAP / 256), dim3(256), 0,
                       stream, out_disp);

    if (use_split) {
        hipLaunchKernelGGL((gemm_tok_kernel<0>), dim3(MTILES * SPLITS), dim3(64),
                           0, stream, x, wg, buf);
        hipLaunchKernelGGL(softmax_kernel, dim3(S_TOK / 256), dim3(256), 0,
                           stream, buf, SPLITS, arg_idx, gateval, cnt_part,
                           gsum_blk);
    } else {
        hipLaunchKernelGGL(zero_kernel, dim3(256), dim3(256), 0, stream,
                           buf, S_TOK * NEXP / 4);
        hipLaunchKernelGGL((gemm_tok_kernel<1>), dim3(MTILES * SPLITS), dim3(64),
                           0, stream, x, wg, buf);
        hipLaunchKernelGGL(softmax_kernel, dim3(S_TOK / 256), dim3(256), 0,
                           stream, buf, 1, arg_idx, gateval, cnt_part,
                           gsum_blk);
    }

    hipLaunchKernelGGL(scan_kernel, dim3(1), dim3(256), 0, stream,
                       cnt_part, gsum_blk, offsets, out_loss);
    hipLaunchKernelGGL(dispatch_kernel, dim3(NB), dim3(64), 0, stream,
                       arg_idx, gateval, offsets, out_gates, out_disp);
}